// Round 5
// baseline (122.715 us; speedup 1.0000x reference)
//
#include <hip/hip_runtime.h>
#include <cstdint>
#include <cstddef>

typedef __attribute__((ext_vector_type(8))) short short8v;
typedef __attribute__((ext_vector_type(4))) unsigned uint4v;
typedef __attribute__((ext_vector_type(4))) float floatx4;

#define LIN 568   // weight row length: 1 + 9*63

__device__ __forceinline__ short f32_to_bf16(float f) {
  unsigned u = __builtin_bit_cast(unsigned, f);
  u += 0x7fffu + ((u >> 16) & 1u);   // RNE (inputs finite)
  return (short)(u >> 16);
}
// Packed RNE f32->bf16 (2 values / instruction), bitwise-identical to manual RNE.
__device__ __forceinline__ unsigned cvt_pk_bf16(float lo, float hi) {
  unsigned r;
  asm("v_cvt_pk_bf16_f32 %0, %1, %2" : "=v"(r) : "v"(lo), "v"(hi));
  return r;
}
// Cross-lane add via DPP (pure VALU, no ds op).
// 0xB1 quad_perm[1,0,3,2]; 0x4E quad_perm[2,3,0,1]; 0x141 row_half_mirror; 0x140 row_mirror.
template<int CTRL>
__device__ __forceinline__ float dpp_add(float v) {
  int y = __builtin_amdgcn_update_dpp(0, __builtin_bit_cast(int, v), CTRL, 0xF, 0xF, true);
  return v + __builtin_bit_cast(float, y);
}

// Pack weight into MFMA-B-fragment-major order (bf16):
//   wfragg[step*2048 + nb*512 + lane*8 + j]
//     = W[n = nb*16 + (lane&15)][k = tap*64 + half*32 + (lane>>4)*8 + j]
// step = tap*2 + half; c==0 column zeroed (time feature is rank-1 epilogue).
__global__ void prep_weight(const float* __restrict__ w, short* __restrict__ wfragg) {
  int i = blockIdx.x * 256 + threadIdx.x;   // 0 .. 36863
  if (i >= 9 * 2 * 4 * 64 * 8) return;
  int j    = i & 7;
  int lane = (i >> 3) & 63;
  int nb   = (i >> 9) & 3;
  int half = (i >> 11) & 1;
  int tap  = i >> 12;
  int n = nb * 16 + (lane & 15);
  int c = half * 32 + ((lane >> 4) << 3) + j;
  float v = (c == 0) ? 0.0f : w[n * LIN + 1 + tap * 63 + (c - 1)];
  wfragg[i] = f32_to_bf16(v);
}

// BARRIER-FREE implicit-GEMM: no LDS x-tile, no __syncthreads.
// Block: 256 threads = 4 waves, strip of 4 output rows; wave wv = row h0+wv,
// 64 px = 4 m-blocks x 4 n-blocks of 16x16x32 bf16 MFMA.
// A-fragments loaded per step directly from x (L2-resident, 32 MB), converted
// with the same RNE cvt as before -> bitwise-identical MFMA inputs to the LDS
// version. 1-step-deep software pipeline on A (parity buffer = step&1), 3-step
// B prefetch. Column edges: clamp addr + zero edge lanes; row edges: wave-
// uniform skip. Waves free-run -> no block-wide convoy, latency hidden by
// 8 independent waves/CU.
__launch_bounds__(256, 2)
__global__ void lconv_main(const float* __restrict__ x, const float* __restrict__ w,
                           const float* __restrict__ bias, const short* __restrict__ wfragg,
                           float* __restrict__ out) {
  __shared__ float tres_s[4 * 64];    // per-wave time-feature row (1 KB, same-wave use)

  const int tid = threadIdx.x;
  const int bb = blockIdx.x >> 4;          // batch 0..31
  const int h0 = (blockIdx.x & 15) << 2;   // first output row of 4-row strip
  const float* xb = x + (size_t)bb * (64 * 64 * 64);

  const int lane = tid & 63;
  const int l15 = lane & 15;
  const int q = lane >> 4;
  const int wv = tid >> 6;   // wave id = strip row

  // ---- early issue: B fragments for steps 0..2 + epilogue constants ----
  const short* wfl = wfragg + lane * 8;
  short8v b0[4], b1[4], b2[4];
#pragma unroll
  for (int nb = 0; nb < 4; ++nb) {
    b0[nb] = *(const short8v*)(wfl + 0 * 2048 + nb * 512);
    b1[nb] = *(const short8v*)(wfl + 1 * 2048 + nb * 512);
    b2[nb] = *(const short8v*)(wfl + 2 * 2048 + nb * 512);
  }
  float bj[4], w0j[4];
#pragma unroll
  for (int nb = 0; nb < 4; ++nb) {
    int n = nb * 16 + l15;
    bj[nb] = bias[n];
    w0j[nb] = w[n * LIN];   // weight[:,0] fp32
  }

  floatx4 acc[4][4];
#pragma unroll
  for (int mb = 0; mb < 4; ++mb)
#pragma unroll
    for (int nb = 0; nb < 4; ++nb) acc[mb][nb] = floatx4{0.f, 0.f, 0.f, 0.f};

  // A raw-fp32 pipeline buffers; parity = step&1 (statically folded after unroll)
  float4 av0[2][4], av1[2][4];

  auto issue_A = [&](int step) {
    if (step >= 18) return;
    const int par = step & 1;
    const int tap = step >> 1, half = step & 1;
    const int kh = tap / 3, kw = tap % 3;
    const int h = h0 + wv + kh - 1;          // wave-uniform
    if ((unsigned)h < 64u) {
      const float* rp = xb + (h * 64) * 64 + half * 32 + q * 8;
#pragma unroll
      for (int mb = 0; mb < 4; ++mb) {
        int col = mb * 16 + l15 + kw - 1;    // in [-1, 64]
        int cc = col < 0 ? 0 : (col > 63 ? 63 : col);
        const float* p = rp + cc * 64;
        av0[par][mb] = *(const float4*)p;
        av1[par][mb] = *(const float4*)(p + 4);
      }
    } else {
#pragma unroll
      for (int mb = 0; mb < 4; ++mb) {
        av0[par][mb] = {0.f, 0.f, 0.f, 0.f};
        av1[par][mb] = {0.f, 0.f, 0.f, 0.f};
      }
    }
  };

  issue_A(0);

#pragma unroll
  for (int step = 0; step < 18; ++step) {
    const int par = step & 1;
    const int tap = step >> 1;
    const int kw = tap % 3;

    // B prefetch (depth 3)
    short8v bn[4];
    if (step + 3 < 18) {
#pragma unroll
      for (int nb = 0; nb < 4; ++nb)
        bn[nb] = *(const short8v*)(wfl + (step + 3) * 2048 + nb * 512);
    }

    // convert current A raws -> bf16 fragments
    short8v a[4];
#pragma unroll
    for (int mb = 0; mb < 4; ++mb) {
      uint4v o;
      o[0] = cvt_pk_bf16(av0[par][mb].x, av0[par][mb].y);
      o[1] = cvt_pk_bf16(av0[par][mb].z, av0[par][mb].w);
      o[2] = cvt_pk_bf16(av1[par][mb].x, av1[par][mb].y);
      o[3] = cvt_pk_bf16(av1[par][mb].z, av1[par][mb].w);
      a[mb] = __builtin_bit_cast(short8v, o);
    }
    short8v z = {0, 0, 0, 0, 0, 0, 0, 0};
    if (kw == 0 && l15 == 0)  a[0] = z;   // col -1 (left pad)
    if (kw == 2 && l15 == 15) a[3] = z;   // col 64 (right pad)

    // issue next step's A loads (other parity buffer; overlaps MFMAs below)
    issue_A(step + 1);

#pragma unroll
    for (int mb = 0; mb < 4; ++mb) {
#pragma unroll
      for (int nb = 0; nb < 4; ++nb)
        acc[mb][nb] = __builtin_amdgcn_mfma_f32_16x16x32_bf16(a[mb], b0[nb], acc[mb][nb], 0, 0, 0);
    }
#pragma unroll
    for (int nb = 0; nb < 4; ++nb) { b0[nb] = b1[nb]; b1[nb] = b2[nb]; b2[nb] = bn[nb]; }
  }

  // ---- per-pixel time feature (fp32 direct from x; lane <-> pixel col) ----
  {
    float ss = 0.f;
#pragma unroll
    for (int dh = 0; dh < 3; ++dh) {
      int hh = h0 + wv + dh - 1;             // wave-uniform
      if ((unsigned)hh < 64u) {
#pragma unroll
        for (int dw = 0; dw < 3; ++dw) {
          int c = lane + dw - 1;
          int cc = c < 0 ? 0 : (c > 63 ? 63 : c);
          float tv = xb[(hh * 64 + cc) * 64];
          tv = ((unsigned)c < 64u) ? tv : 0.f;   // col pad -> 0
          tv = fmaxf(tv, 1.0f);
          ss += tv * tv;
        }
      } else {
        ss += 3.0f;   // 3 zero-pad taps -> fmax(0,1)^2 each
      }
    }
    tres_s[wv * 64 + lane] = sqrtf(ss - 8.0f);   // same-wave producer/consumer
  }

  // ---- epilogue: bias + rank-1 time term, Lorentz norm (DPP reduce), store ----
#pragma unroll
  for (int mb = 0; mb < 4; ++mb) {
    float4 t4 = *(const float4*)&tres_s[wv * 64 + mb * 16 + q * 4];
#pragma unroll
    for (int r = 0; r < 4; ++r) {
      int pcol = mb * 16 + q * 4 + r;      // C/D row m = quad*4 + reg
      float tr = t4[r];
      float v0 = acc[mb][0][r] + bj[0] + tr * w0j[0];
      float v1 = acc[mb][1][r] + bj[1] + tr * w0j[1];
      float v2 = acc[mb][2][r] + bj[2] + tr * w0j[2];
      float v3 = acc[mb][3][r] + bj[3] + tr * w0j[3];
      float ss = v0 * v0 + v1 * v1 + v2 * v2 + v3 * v3;
      ss = dpp_add<0xB1>(ss);    // + lane^1
      ss = dpp_add<0x4E>(ss);    // + lane^2
      ss = dpp_add<0x141>(ss);   // + mirror-8
      ss = dpp_add<0x140>(ss);   // + mirror-16 (full 16-lane sum)
      float* ob = out + (size_t)((bb * 64 + h0 + wv) * 64 + pcol) * 65;
      if (l15 == 0) ob[0] = sqrtf(ss + 1.0f);
      ob[1 + l15]  = v0;
      ob[17 + l15] = v1;
      ob[33 + l15] = v2;
      ob[49 + l15] = v3;
    }
  }
}

extern "C" void kernel_launch(void* const* d_in, const int* in_sizes, int n_in,
                              void* d_out, int out_size, void* d_ws, size_t ws_size,
                              hipStream_t stream) {
  const float* x = (const float*)d_in[0];
  const float* w = (const float*)d_in[1];
  const float* b = (const float*)d_in[2];
  float* out = (float*)d_out;
  short* wfragg = (short*)d_ws;   // 73728 B fragment-packed bf16 weight

  prep_weight<<<144, 256, 0, stream>>>(w, wfragg);
  lconv_main<<<32 * 16, 256, 0, stream>>>(x, w, b, wfragg, out);
}

// Round 6
// 101.325 us; speedup vs baseline: 1.2111x; 1.2111x over previous
//
#include <hip/hip_runtime.h>
#include <cstdint>
#include <cstddef>

typedef __attribute__((ext_vector_type(8))) short short8v;
typedef __attribute__((ext_vector_type(4))) unsigned uint4v;
typedef __attribute__((ext_vector_type(4))) float floatx4;

#define LIN 568   // weight row length: 1 + 9*63

__device__ __forceinline__ short f32_to_bf16(float f) {
  unsigned u = __builtin_bit_cast(unsigned, f);
  u += 0x7fffu + ((u >> 16) & 1u);   // RNE (inputs finite)
  return (short)(u >> 16);
}
// Packed RNE f32->bf16 (2 values / instruction), bitwise-identical to manual RNE.
__device__ __forceinline__ unsigned cvt_pk_bf16(float lo, float hi) {
  unsigned r;
  asm("v_cvt_pk_bf16_f32 %0, %1, %2" : "=v"(r) : "v"(lo), "v"(hi));
  return r;
}
// Cross-lane add via DPP (pure VALU, no ds op).
template<int CTRL>
__device__ __forceinline__ float dpp_add(float v) {
  int y = __builtin_amdgcn_update_dpp(0, __builtin_bit_cast(int, v), CTRL, 0xF, 0xF, true);
  return v + __builtin_bit_cast(float, y);
}
// Register-free global->LDS 16B copy (per-lane global addr, lane-linear LDS dest).
__device__ __forceinline__ void gload_lds16(const short* g, short* lds) {
  __builtin_amdgcn_global_load_lds(
      (const __attribute__((address_space(1))) void*)g,
      (__attribute__((address_space(3))) void*)lds, 16, 0, 0);
}

// Fused pre-pass.
// Blocks 0..2047: convert x fp32 -> bf16 (RNE) into xbf[32][64][64][64] (16.78 MB).
// Blocks 2048..2191: pack weight into MFMA-B-fragment-major bf16 (wfragg):
//   wfragg[step*2048 + nb*512 + lane*8 + j]
//     = W[n = nb*16 + (lane&15)][k = tap*64 + half*32 + (lane>>4)*8 + j]
// step = tap*2 + half; c==0 column zeroed (time feature is rank-1 epilogue).
__global__ void prep_all(const float* __restrict__ x, const float* __restrict__ w,
                         short* __restrict__ wfragg, short* __restrict__ xbf) {
  int bid = blockIdx.x;
  if (bid < 2048) {
    int t = bid * 256 + threadIdx.x;           // 0..524287; 16 floats each = 2^23 total
    const float* p = x + (size_t)t * 16;
    float4 v0 = *(const float4*)p;
    float4 v1 = *(const float4*)(p + 4);
    float4 v2 = *(const float4*)(p + 8);
    float4 v3 = *(const float4*)(p + 12);
    uint4v o0, o1;
    o0[0] = cvt_pk_bf16(v0.x, v0.y); o0[1] = cvt_pk_bf16(v0.z, v0.w);
    o0[2] = cvt_pk_bf16(v1.x, v1.y); o0[3] = cvt_pk_bf16(v1.z, v1.w);
    o1[0] = cvt_pk_bf16(v2.x, v2.y); o1[1] = cvt_pk_bf16(v2.z, v2.w);
    o1[2] = cvt_pk_bf16(v3.x, v3.y); o1[3] = cvt_pk_bf16(v3.z, v3.w);
    short* ob = xbf + (size_t)t * 16;
    *(uint4v*)ob = o0;
    *(uint4v*)(ob + 8) = o1;
  } else {
    int i = (bid - 2048) * 256 + threadIdx.x;   // 0 .. 36863
    if (i >= 9 * 2 * 4 * 64 * 8) return;
    int j    = i & 7;
    int lane = (i >> 3) & 63;
    int nb   = (i >> 9) & 3;
    int half = (i >> 11) & 1;
    int tap  = i >> 12;
    int n = nb * 16 + (lane & 15);
    int c = half * 32 + ((lane >> 4) << 3) + j;
    float v = (c == 0) ? 0.0f : w[n * LIN + 1 + tap * 63 + (c - 1)];
    wfragg[i] = f32_to_bf16(v);
  }
}

// Block: 256 threads = 4 waves, strip of 4 output rows x 65 out-ch. Grid 512.
// Staging via global_load_lds (ZERO VGPR cost -> all 12 ops/wave in flight at
// once; no compiler load-serialization): LDS tile [6 rows][64 cols][8 chunks]
// of 16B, linear dest, source chunk pre-permuted g^(col&7) so swizzled reads
// are <=2-way bank aliasing. Data is pre-converted bf16 (xbf) -> no cvt in
// this kernel at all. Single barrier; 18-step MFMA loop runs uninterrupted.
// Column edges: clamp addr + zero edge lanes (R5-verified); row edges: clamp
// + block-uniform LDS zero of the pad row.
__launch_bounds__(256, 2)
__global__ void lconv_main(const short* __restrict__ xbf, const float* __restrict__ w,
                           const float* __restrict__ bias, const short* __restrict__ wfragg,
                           float* __restrict__ out) {
  __shared__ short xt[6 * 64 * 64];   // 49152 B : [row][col][chunk] 16B chunks, swizzled
  __shared__ float tres_s[4 * 64];    // per-wave time-feature row (1 KB, same-wave use)

  const int tid = threadIdx.x;
  const int bb = blockIdx.x >> 4;          // batch 0..31
  const int h0 = (blockIdx.x & 15) << 2;   // first output row of 4-row strip
  const short* xb2 = xbf + (size_t)bb * (64 * 64 * 64);

  const int lane = tid & 63;
  const int l15 = lane & 15;
  const int q = lane >> 4;
  const int wv = tid >> 6;   // wave id = strip row

  // ---- staging: 12 global_load_lds per wave (48 KB block tile), zero VGPRs ----
#pragma unroll
  for (int i = 0; i < 12; ++i) {
    int c = wv * 768 + i * 64 + lane;   // chunk id 0..3071
    int row = c >> 9;
    int rem = c & 511;
    int col = rem >> 3;
    int g   = rem & 7;
    int h = h0 - 1 + row;
    int hc = h < 0 ? 0 : (h > 63 ? 63 : h);      // clamp; pad rows zeroed below
    const short* gp = xb2 + ((hc * 64 + col) << 6) + ((g ^ (col & 7)) << 3);
    gload_lds16(gp, &xt[(wv * 768 + i * 64) << 3]);   // wave-uniform LDS base
  }

  // ---- early issue: B fragments for steps 0..2 + epilogue constants ----
  const short* wfl = wfragg + lane * 8;
  short8v b0[4], b1[4], b2[4];
#pragma unroll
  for (int nb = 0; nb < 4; ++nb) {
    b0[nb] = *(const short8v*)(wfl + 0 * 2048 + nb * 512);
    b1[nb] = *(const short8v*)(wfl + 1 * 2048 + nb * 512);
    b2[nb] = *(const short8v*)(wfl + 2 * 2048 + nb * 512);
  }
  float bj[4], w0j[4];
#pragma unroll
  for (int nb = 0; nb < 4; ++nb) {
    int n = nb * 16 + l15;
    bj[nb] = bias[n];
    w0j[nb] = w[n * LIN];   // weight[:,0] fp32
  }

  __syncthreads();   // drains vmcnt: whole tile + B0..2 resident

  // ---- zero the pad row for edge strips (block-uniform branch) ----
  if (h0 == 0 || h0 == 60) {
    int row = (h0 == 0) ? 0 : 5;
    short8v z = {0, 0, 0, 0, 0, 0, 0, 0};
#pragma unroll
    for (int k = 0; k < 2; ++k)
      *(short8v*)&xt[(row * 512 + k * 256 + tid) << 3] = z;
    __syncthreads();
  }

  floatx4 acc[4][4];
#pragma unroll
  for (int mb = 0; mb < 4; ++mb)
#pragma unroll
    for (int nb = 0; nb < 4; ++nb) acc[mb][nb] = floatx4{0.f, 0.f, 0.f, 0.f};

  auto do_step = [&](int step) {
    const int tap = step >> 1, half = step & 1;
    const int kh = tap / 3, kw = tap % 3;

    short8v bn[4];
    if (step + 3 < 18) {
#pragma unroll
      for (int nb = 0; nb < 4; ++nb)
        bn[nb] = *(const short8v*)(wfl + (step + 3) * 2048 + nb * 512);
    }

    const int lr = (wv + kh) << 9;        // LDS row base (row*512 chunks)
    const int ch = (half << 2) + q;       // k-chunk 0..7
    short8v a[4];
#pragma unroll
    for (int mb = 0; mb < 4; ++mb) {
      int pc = mb * 16 + l15 + kw - 1;            // pixel col in [-1,64]
      int cc = pc < 0 ? 0 : (pc > 63 ? 63 : pc);
      a[mb] = *(const short8v*)&xt[(lr + cc * 8 + (ch ^ (cc & 7))) << 3];
    }
    short8v z = {0, 0, 0, 0, 0, 0, 0, 0};
    if (kw == 0 && l15 == 0)  a[0] = z;   // col -1 (left pad)
    if (kw == 2 && l15 == 15) a[3] = z;   // col 64 (right pad)

#pragma unroll
    for (int mb = 0; mb < 4; ++mb) {
#pragma unroll
      for (int nb = 0; nb < 4; ++nb)
        acc[mb][nb] = __builtin_amdgcn_mfma_f32_16x16x32_bf16(a[mb], b0[nb], acc[mb][nb], 0, 0, 0);
    }
#pragma unroll
    for (int nb = 0; nb < 4; ++nb) { b0[nb] = b1[nb]; b1[nb] = b2[nb]; b2[nb] = bn[nb]; }
  };

#pragma unroll
  for (int step = 0; step < 18; ++step) do_step(step);

  // ---- per-pixel time feature (bf16 ch-0 taps from LDS; lane <-> pixel col) ----
  {
    float ss = 0.f;
#pragma unroll
    for (int dh = 0; dh < 3; ++dh) {
      int lr2 = (wv + dh) << 9;
#pragma unroll
      for (int dw = 0; dw < 3; ++dw) {
        int c = lane + dw - 1;
        int cc = c < 0 ? 0 : (c > 63 ? 63 : c);
        // source chunk 0 of (row,cc) lives at swizzled slot g = cc&7; elem 0 = ch 0
        short tvs = xt[(lr2 + cc * 8 + (cc & 7)) << 3];
        float tv = __builtin_bit_cast(float, ((unsigned)(unsigned short)tvs) << 16);
        tv = ((unsigned)c < 64u) ? tv : 0.f;   // col pad -> 0
        tv = fmaxf(tv, 1.0f);
        ss += tv * tv;
      }
    }
    tres_s[wv * 64 + lane] = sqrtf(ss - 8.0f);   // same-wave producer/consumer
  }

  // ---- epilogue: bias + rank-1 time term, Lorentz norm (DPP reduce), store ----
#pragma unroll
  for (int mb = 0; mb < 4; ++mb) {
    float4 t4 = *(const float4*)&tres_s[wv * 64 + mb * 16 + q * 4];
#pragma unroll
    for (int r = 0; r < 4; ++r) {
      int pcol = mb * 16 + q * 4 + r;      // C/D row m = quad*4 + reg
      float tr = t4[r];
      float v0 = acc[mb][0][r] + bj[0] + tr * w0j[0];
      float v1 = acc[mb][1][r] + bj[1] + tr * w0j[1];
      float v2 = acc[mb][2][r] + bj[2] + tr * w0j[2];
      float v3 = acc[mb][3][r] + bj[3] + tr * w0j[3];
      float ss = v0 * v0 + v1 * v1 + v2 * v2 + v3 * v3;
      ss = dpp_add<0xB1>(ss);    // + lane^1
      ss = dpp_add<0x4E>(ss);    // + lane^2
      ss = dpp_add<0x141>(ss);   // + mirror-8
      ss = dpp_add<0x140>(ss);   // + mirror-16 (full 16-lane sum)
      float* ob = out + (size_t)((bb * 64 + h0 + wv) * 64 + pcol) * 65;
      if (l15 == 0) ob[0] = sqrtf(ss + 1.0f);
      ob[1 + l15]  = v0;
      ob[17 + l15] = v1;
      ob[33 + l15] = v2;
      ob[49 + l15] = v3;
    }
  }
}

extern "C" void kernel_launch(void* const* d_in, const int* in_sizes, int n_in,
                              void* d_out, int out_size, void* d_ws, size_t ws_size,
                              hipStream_t stream) {
  const float* x = (const float*)d_in[0];
  const float* w = (const float*)d_in[1];
  const float* b = (const float*)d_in[2];
  float* out = (float*)d_out;
  // workspace layout: [wfragg 73728 B][xbf 16777216 B]  (poison fill proves ws >= 256 MB)
  short* wfragg = (short*)d_ws;
  short* xbf = (short*)((char*)d_ws + 73728);

  prep_all<<<2048 + 144, 256, 0, stream>>>(x, w, wfragg, xbf);
  lconv_main<<<32 * 16, 256, 0, stream>>>(xbf, w, b, wfragg, out);
}

// Round 7
// 99.582 us; speedup vs baseline: 1.2323x; 1.0175x over previous
//
#include <hip/hip_runtime.h>
#include <cstdint>
#include <cstddef>

typedef __attribute__((ext_vector_type(8))) short short8v;
typedef __attribute__((ext_vector_type(4))) unsigned uint4v;
typedef __attribute__((ext_vector_type(4))) float floatx4;

#define LIN 568   // weight row length: 1 + 9*63

__device__ __forceinline__ short f32_to_bf16(float f) {
  unsigned u = __builtin_bit_cast(unsigned, f);
  u += 0x7fffu + ((u >> 16) & 1u);   // RNE (inputs finite)
  return (short)(u >> 16);
}
// Packed RNE f32->bf16 (2 values / instruction), bitwise-identical to manual RNE.
__device__ __forceinline__ unsigned cvt_pk_bf16(float lo, float hi) {
  unsigned r;
  asm("v_cvt_pk_bf16_f32 %0, %1, %2" : "=v"(r) : "v"(lo), "v"(hi));
  return r;
}
// Cross-lane add via DPP (pure VALU, no ds op).
template<int CTRL>
__device__ __forceinline__ float dpp_add(float v) {
  int y = __builtin_amdgcn_update_dpp(0, __builtin_bit_cast(int, v), CTRL, 0xF, 0xF, true);
  return v + __builtin_bit_cast(float, y);
}

// Pack weight into MFMA-B-fragment-major order (bf16):
//   wfragg[step*2048 + nb*512 + lane*8 + j]
//     = W[n = nb*16 + (lane&15)][k = tap*64 + half*32 + (lane>>4)*8 + j]
// step = tap*2 + half; c==0 column zeroed (time feature is rank-1 epilogue).
__global__ void prep_weight(const float* __restrict__ w, short* __restrict__ wfragg) {
  int i = blockIdx.x * 256 + threadIdx.x;   // 0 .. 36863
  if (i >= 9 * 2 * 4 * 64 * 8) return;
  int j    = i & 7;
  int lane = (i >> 3) & 63;
  int nb   = (i >> 9) & 3;
  int half = (i >> 11) & 1;
  int tap  = i >> 12;
  int n = nb * 16 + (lane & 15);
  int c = half * 32 + ((lane >> 4) << 3) + j;
  float v = (c == 0) ? 0.0f : w[n * LIN + 1 + tap * 63 + (c - 1)];
  wfragg[i] = f32_to_bf16(v);
}

// PERSISTENT blocks: grid 256 = 1 block/CU; each block = 4 waves, processes TWO
// adjacent 4-row strips (2*bid, 2*bid+1) of one batch image, double-buffered.
// Cross-strip pipeline: strip-1's 24 global staging loads are issued BEFORE
// strip-0's 18-step MFMA loop and waited only after it (~10us cover); strip-0's
// stores drain under strip-1's compute. 2 barriers per block total.
// LDS x-tiles use the R6-verified swizzled chunk layout: [row][col][slot g] of
// 16B chunks, slot g holds source channel-chunk g^(col&7) -> ds_read_b128 at
// <=2-way bank aliasing. OOB rows staged as zeros (R4-verified); column edges
// clamp+lane-zero at read (R6-verified). Epilogue: DPP reduce + LDS tres.
__launch_bounds__(256, 1)
__global__ void lconv_main(const float* __restrict__ x, const float* __restrict__ w,
                           const float* __restrict__ bias, const short* __restrict__ wfragg,
                           float* __restrict__ out) {
  __shared__ short xt0[3072 * 8];     // 49152 B : strip buffer 0
  __shared__ short xt1[3072 * 8];     // 49152 B : strip buffer 1
  __shared__ float tres_s[4 * 64];    // per-wave time-feature row (same-wave use)

  const int tid = threadIdx.x;
  const int bid = blockIdx.x;          // 0..255
  const int bb  = bid >> 3;            // batch 0..31
  const int h0a = (bid & 7) << 3;      // strip pair: rows h0a..h0a+3 and h0a+4..h0a+7
  const int h0b = h0a + 4;
  const float* xb = x + (size_t)bb * (64 * 64 * 64);

  const int lane = tid & 63;
  const int l15 = lane & 15;
  const int q = lane >> 4;
  const int wv = tid >> 6;   // wave id = strip row

  // ---- staging registers (held across compute; 1 wave/SIMD -> ~512 VGPR budget)
  float4 s0v[12], s1v[12];

  // idx = i*256+tid == chunk id == row*512 + col*8 + g  (6 rows x 64 cols x 8 slots)
  auto stage_regs = [&](int h0s) {
#pragma unroll
    for (int i = 0; i < 12; ++i) {
      int idx = i * 256 + tid;
      int row = idx >> 9;
      int rem = idx & 511;
      int col = rem >> 3;
      int g   = rem & 7;
      int h = h0s - 1 + row;
      s0v[i] = {0.f, 0.f, 0.f, 0.f};
      s1v[i] = {0.f, 0.f, 0.f, 0.f};
      if ((unsigned)h < 64u) {
        // slot g holds source chunk g^(col&7)  (swizzle applied on the source side)
        const float* p = xb + (((h * 64 + col) << 6) + ((g ^ (col & 7)) << 3));
        s0v[i] = *(const float4*)p;
        s1v[i] = *(const float4*)(p + 4);
      }
    }
  };
  auto cvt_write = [&](short* dst) {
#pragma unroll
    for (int i = 0; i < 12; ++i) {
      int idx = i * 256 + tid;
      uint4v o;
      o[0] = cvt_pk_bf16(s0v[i].x, s0v[i].y);
      o[1] = cvt_pk_bf16(s0v[i].z, s0v[i].w);
      o[2] = cvt_pk_bf16(s1v[i].x, s1v[i].y);
      o[3] = cvt_pk_bf16(s1v[i].z, s1v[i].w);
      *(uint4v*)&dst[idx << 3] = o;
    }
  };

  // ---- B rotation (depth 4) + epilogue constants ----
  const short* wfl = wfragg + lane * 8;
  short8v b0[4], b1[4], b2[4], b3[4];
  auto loadB = [&]() {
#pragma unroll
    for (int nb = 0; nb < 4; ++nb) {
      b0[nb] = *(const short8v*)(wfl + 0 * 2048 + nb * 512);
      b1[nb] = *(const short8v*)(wfl + 1 * 2048 + nb * 512);
      b2[nb] = *(const short8v*)(wfl + 2 * 2048 + nb * 512);
      b3[nb] = *(const short8v*)(wfl + 3 * 2048 + nb * 512);
    }
  };
  float bj[4], w0j[4];

  // ---- strip body: 18-step MFMA + tres + epilogue ----
  auto run_strip = [&](int h0s, const short* buf, bool reloadB) {
    floatx4 acc[4][4];
#pragma unroll
    for (int mb = 0; mb < 4; ++mb)
#pragma unroll
      for (int nb = 0; nb < 4; ++nb) acc[mb][nb] = floatx4{0.f, 0.f, 0.f, 0.f};

#pragma unroll
    for (int step = 0; step < 18; ++step) {
      const int tap = step >> 1, half = step & 1;
      const int kh = tap / 3, kw = tap % 3;

      short8v bn[4];
      if (step + 4 < 18) {
#pragma unroll
        for (int nb = 0; nb < 4; ++nb)
          bn[nb] = *(const short8v*)(wfl + (step + 4) * 2048 + nb * 512);
      }

      const int lr = (wv + kh) << 9;        // LDS row base (row*512 chunks)
      const int ch = (half << 2) + q;       // wanted k-chunk 0..7
      short8v a[4];
#pragma unroll
      for (int mb = 0; mb < 4; ++mb) {
        int pc = mb * 16 + l15 + kw - 1;            // pixel col in [-1,64]
        int cc = pc < 0 ? 0 : (pc > 63 ? 63 : pc);
        a[mb] = *(const short8v*)&buf[(lr + cc * 8 + (ch ^ (cc & 7))) << 3];
      }
      short8v z = {0, 0, 0, 0, 0, 0, 0, 0};
      if (kw == 0 && l15 == 0)  a[0] = z;   // col -1 (left pad)
      if (kw == 2 && l15 == 15) a[3] = z;   // col 64 (right pad)

#pragma unroll
      for (int mb = 0; mb < 4; ++mb) {
#pragma unroll
        for (int nb = 0; nb < 4; ++nb)
          acc[mb][nb] = __builtin_amdgcn_mfma_f32_16x16x32_bf16(a[mb], b0[nb], acc[mb][nb], 0, 0, 0);
      }
#pragma unroll
      for (int nb = 0; nb < 4; ++nb) { b0[nb] = b1[nb]; b1[nb] = b2[nb]; b2[nb] = b3[nb]; b3[nb] = bn[nb]; }
    }

    if (reloadB) loadB();   // for next strip; overlaps tres+epilogue+barrier

    // per-pixel time feature (ch-0 taps; OOB rows are staged zeros -> fmax->1)
    {
      float ss = 0.f;
#pragma unroll
      for (int dh = 0; dh < 3; ++dh) {
        int lr2 = (wv + dh) << 9;
#pragma unroll
        for (int dw = 0; dw < 3; ++dw) {
          int c = lane + dw - 1;
          int cc = c < 0 ? 0 : (c > 63 ? 63 : c);
          short tvs = buf[(lr2 + cc * 8 + (cc & 7)) << 3];   // slot cc&7 = source chunk 0
          float tv = __builtin_bit_cast(float, ((unsigned)(unsigned short)tvs) << 16);
          tv = ((unsigned)c < 64u) ? tv : 0.f;   // col pad -> 0
          tv = fmaxf(tv, 1.0f);
          ss += tv * tv;
        }
      }
      tres_s[wv * 64 + lane] = sqrtf(ss - 8.0f);   // same-wave producer/consumer
    }

    // epilogue: bias + rank-1 time term, Lorentz norm (DPP reduce), store
#pragma unroll
    for (int mb = 0; mb < 4; ++mb) {
      float4 t4 = *(const float4*)&tres_s[wv * 64 + mb * 16 + q * 4];
#pragma unroll
      for (int r = 0; r < 4; ++r) {
        int pcol = mb * 16 + q * 4 + r;      // C/D row m = quad*4 + reg
        float tr = t4[r];
        float v0 = acc[mb][0][r] + bj[0] + tr * w0j[0];
        float v1 = acc[mb][1][r] + bj[1] + tr * w0j[1];
        float v2 = acc[mb][2][r] + bj[2] + tr * w0j[2];
        float v3 = acc[mb][3][r] + bj[3] + tr * w0j[3];
        float ss = v0 * v0 + v1 * v1 + v2 * v2 + v3 * v3;
        ss = dpp_add<0xB1>(ss);    // + lane^1
        ss = dpp_add<0x4E>(ss);    // + lane^2
        ss = dpp_add<0x141>(ss);   // + mirror-8
        ss = dpp_add<0x140>(ss);   // + mirror-16 (full 16-lane sum)
        float* ob = out + (size_t)((bb * 64 + h0s + wv) * 64 + pcol) * 65;
        if (l15 == 0) ob[0] = sqrtf(ss + 1.0f);
        ob[1 + l15]  = v0;
        ob[17 + l15] = v1;
        ob[33 + l15] = v2;
        ob[49 + l15] = v3;
      }
    }
  };

  // ================== persistent 2-strip pipeline ==================
  stage_regs(h0a);          // strip-0 staging loads in flight
  loadB();                  // B steps 0..3 + constants (L2)
#pragma unroll
  for (int nb = 0; nb < 4; ++nb) {
    int n = nb * 16 + l15;
    bj[nb] = bias[n];
    w0j[nb] = w[n * LIN];   // weight[:,0] fp32
  }
  cvt_write(xt0);           // waits strip-0 loads, writes buffer 0
  __syncthreads();          // buffer 0 visible

  stage_regs(h0b);          // strip-1 loads: in flight across ALL of strip-0 compute
  run_strip(h0a, xt0, true);
  cvt_write(xt1);           // loads long since landed; write buffer 1
  __syncthreads();          // buffer 1 visible (also drains strip-0 stores)

  run_strip(h0b, xt1, false);
}

extern "C" void kernel_launch(void* const* d_in, const int* in_sizes, int n_in,
                              void* d_out, int out_size, void* d_ws, size_t ws_size,
                              hipStream_t stream) {
  const float* x = (const float*)d_in[0];
  const float* w = (const float*)d_in[1];
  const float* b = (const float*)d_in[2];
  float* out = (float*)d_out;
  short* wfragg = (short*)d_ws;   // 73728 B fragment-packed bf16 weight

  prep_weight<<<144, 256, 0, stream>>>(w, wfragg);
  lconv_main<<<256, 256, 0, stream>>>(x, w, b, wfragg, out);
}

// Round 8
// 95.578 us; speedup vs baseline: 1.2839x; 1.0419x over previous
//
#include <hip/hip_runtime.h>
#include <cstdint>
#include <cstddef>

typedef __attribute__((ext_vector_type(8))) short short8v;
typedef __attribute__((ext_vector_type(4))) unsigned uint4v;
typedef __attribute__((ext_vector_type(4))) float floatx4;

#define LIN 568   // weight row length: 1 + 9*63

__device__ __forceinline__ short f32_to_bf16(float f) {
  unsigned u = __builtin_bit_cast(unsigned, f);
  u += 0x7fffu + ((u >> 16) & 1u);   // RNE (inputs finite)
  return (short)(u >> 16);
}
__device__ __forceinline__ float bf16_to_f32(short s) {
  return __builtin_bit_cast(float, ((unsigned)(unsigned short)s) << 16);
}
// Packed RNE f32->bf16 (2 values / instruction), bitwise-identical to manual RNE.
__device__ __forceinline__ unsigned cvt_pk_bf16(float lo, float hi) {
  unsigned r;
  asm("v_cvt_pk_bf16_f32 %0, %1, %2" : "=v"(r) : "v"(lo), "v"(hi));
  return r;
}
// Cross-lane add via DPP (pure VALU, no ds op).
template<int CTRL>
__device__ __forceinline__ float dpp_add(float v) {
  int y = __builtin_amdgcn_update_dpp(0, __builtin_bit_cast(int, v), CTRL, 0xF, 0xF, true);
  return v + __builtin_bit_cast(float, y);
}

// Pack weight into MFMA-B-fragment-major order (bf16):
//   wfragg[step*2048 + nb*512 + lane*8 + j]
//     = W[n = nb*16 + (lane&15)][k = tap*64 + half*32 + (lane>>4)*8 + j]
// step = tap*2 + half; c==0 column zeroed (time feature is rank-1 epilogue).
__global__ void prep_weight(const float* __restrict__ w, short* __restrict__ wfragg) {
  int i = blockIdx.x * 256 + threadIdx.x;   // 0 .. 36863
  if (i >= 9 * 2 * 4 * 64 * 8) return;
  int j    = i & 7;
  int lane = (i >> 3) & 63;
  int nb   = (i >> 9) & 3;
  int half = (i >> 11) & 1;
  int tap  = i >> 12;
  int n = nb * 16 + (lane & 15);
  int c = half * 32 + ((lane >> 4) << 3) + j;
  float v = (c == 0) ? 0.0f : w[n * LIN + 1 + tap * 63 + (c - 1)];
  wfragg[i] = f32_to_bf16(v);
}

// R4 champion structure; ONLY the epilogue store path changed:
// results are scattered into an LDS row image (aliasing the x-tile after its
// last use) and then streamed to global as fully-coalesced dwordx4 stores
// (64 lanes x 16B = 1KB/inst, dense) instead of 64 scalar 260B-stride stores.
__launch_bounds__(256, 2)
__global__ void lconv_main(const float* __restrict__ x, const float* __restrict__ w,
                           const float* __restrict__ bias, const short* __restrict__ wfragg,
                           float* __restrict__ out) {
  // 66560 B: holds short xt[6*66*72] (57024 B) during compute, then aliased as
  // float ostg[4][4160] (66560 B) for the store-staging epilogue.
  __shared__ __align__(16) char shmem[4 * 4160 * 4];
  __shared__ float tres_s[4 * 64];    // per-wave time-feature row (1 KB)
  short* xt = (short*)shmem;

  const int tid = threadIdx.x;
  const int bb = blockIdx.x >> 4;          // batch 0..31
  const int h0 = (blockIdx.x & 15) << 2;   // first output row of 4-row strip
  const float* xb = x + (size_t)bb * (64 * 64 * 64);

  const int lane = tid & 63;
  const int l15 = lane & 15;
  const int q = lane >> 4;
  const int wv = tid >> 6;   // wave id = strip row

  // ---- issue ALL staging loads up front (T14 issue-early) ----
  float4 s0[12], s1[12];
#pragma unroll
  for (int i = 0; i < 12; ++i) {
    int idx = i * 256 + tid;       // 0..3071 : rows 0..5 x 64 cols x 8 ch8-groups
    int row = idx >> 9;
    int rem = idx & 511;
    int col = rem >> 3;
    int ch8 = (rem & 7) << 3;
    int h = h0 - 1 + row;
    s0[i] = {0.f, 0.f, 0.f, 0.f};
    s1[i] = {0.f, 0.f, 0.f, 0.f};
    if ((unsigned)h < 64u) {
      const float* p = xb + ((h * 64 + col) * 64 + ch8);
      s0[i] = *(const float4*)p;
      s1[i] = *(const float4*)(p + 4);
    }
  }

  // ---- early issue: B fragments for steps 0..2 + epilogue constants ----
  const short* wfl = wfragg + lane * 8;
  short8v b0[4], b1[4], b2[4];
#pragma unroll
  for (int nb = 0; nb < 4; ++nb) {
    b0[nb] = *(const short8v*)(wfl + 0 * 2048 + nb * 512);
    b1[nb] = *(const short8v*)(wfl + 1 * 2048 + nb * 512);
    b2[nb] = *(const short8v*)(wfl + 2 * 2048 + nb * 512);
  }
  float bj[4], w0j[4];
#pragma unroll
  for (int nb = 0; nb < 4; ++nb) {
    int n = nb * 16 + l15;
    bj[nb] = bias[n];
    w0j[nb] = w[n * LIN];   // weight[:,0] fp32
  }

  // ---- phase-1 convert+write: LDS rows 0..3 (x rows h0-1..h0+2) ----
#pragma unroll
  for (int i = 0; i < 8; ++i) {
    int idx = i * 256 + tid;
    int row = idx >> 9;
    int rem = idx & 511;
    int col = rem >> 3;
    int ch8 = (rem & 7) << 3;
    uint4v o;
    o[0] = cvt_pk_bf16(s0[i].x, s0[i].y);
    o[1] = cvt_pk_bf16(s0[i].z, s0[i].w);
    o[2] = cvt_pk_bf16(s1[i].x, s1[i].y);
    o[3] = cvt_pk_bf16(s1[i].z, s1[i].w);
    *(uint4v*)&xt[(row * 66 + col + 1) * 72 + ch8] = o;
  }
  if (tid < 64) {   // pads for rows 0..3, cols 0 and 65
    int r = tid >> 4;
    int cc = (tid >> 3) & 1;
    int ch8 = (tid & 7) << 3;
    short8v z = {0, 0, 0, 0, 0, 0, 0, 0};
    *(short8v*)&xt[(r * 66 + cc * 65) * 72 + ch8] = z;
  }
  __syncthreads();   // rows 0..3 visible -> kh=0 taps computable for all waves

  floatx4 acc[4][4];
#pragma unroll
  for (int mb = 0; mb < 4; ++mb)
#pragma unroll
    for (int nb = 0; nb < 4; ++nb) acc[mb][nb] = floatx4{0.f, 0.f, 0.f, 0.f};

  auto do_step = [&](int step) {
    const int tap = step >> 1, half = step & 1;
    const int kh = tap / 3, kw = tap % 3;

    short8v bn[4];
    if (step + 3 < 18) {
#pragma unroll
      for (int nb = 0; nb < 4; ++nb)
        bn[nb] = *(const short8v*)(wfl + (step + 3) * 2048 + nb * 512);
    }

    const short* ab = &xt[((wv + kh) * 66 + kw + l15) * 72 + half * 32 + q * 8];
    short8v a[4];
#pragma unroll
    for (int mb = 0; mb < 4; ++mb)
      a[mb] = *(const short8v*)(ab + mb * 16 * 72);

#pragma unroll
    for (int mb = 0; mb < 4; ++mb) {
#pragma unroll
      for (int nb = 0; nb < 4; ++nb)
        acc[mb][nb] = __builtin_amdgcn_mfma_f32_16x16x32_bf16(a[mb], b0[nb], acc[mb][nb], 0, 0, 0);
    }
#pragma unroll
    for (int nb = 0; nb < 4; ++nb) { b0[nb] = b1[nb]; b1[nb] = b2[nb]; b2[nb] = bn[nb]; }
  };

  // kh=0 taps (steps 0..5): only need LDS rows 0..3
#pragma unroll
  for (int step = 0; step < 6; ++step) do_step(step);

  // ---- phase-2 write-late: LDS rows 4..5 (loads issued at top, long complete) ----
#pragma unroll
  for (int i = 8; i < 12; ++i) {
    int idx = i * 256 + tid;
    int row = idx >> 9;
    int rem = idx & 511;
    int col = rem >> 3;
    int ch8 = (rem & 7) << 3;
    uint4v o;
    o[0] = cvt_pk_bf16(s0[i].x, s0[i].y);
    o[1] = cvt_pk_bf16(s0[i].z, s0[i].w);
    o[2] = cvt_pk_bf16(s1[i].x, s1[i].y);
    o[3] = cvt_pk_bf16(s1[i].z, s1[i].w);
    *(uint4v*)&xt[(row * 66 + col + 1) * 72 + ch8] = o;
  }
  if (tid < 32) {   // pads for rows 4..5
    int r = 4 + (tid >> 4);
    int cc = (tid >> 3) & 1;
    int ch8 = (tid & 7) << 3;
    short8v z = {0, 0, 0, 0, 0, 0, 0, 0};
    *(short8v*)&xt[(r * 66 + cc * 65) * 72 + ch8] = z;
  }
  __syncthreads();   // rows 4..5 visible

#pragma unroll
  for (int step = 6; step < 18; ++step) do_step(step);

  // ---- per-pixel time feature (this wave's row; lane <-> pixel col) ----
  {
    float ss = 0.f;
#pragma unroll
    for (int dh = 0; dh < 3; ++dh)
#pragma unroll
      for (int dw = 0; dw < 3; ++dw) {
        float tv = bf16_to_f32(xt[((wv + dh) * 66 + lane + dw) * 72]);
        tv = fmaxf(tv, 1.0f);
        ss += tv * tv;
      }
    tres_s[wv * 64 + lane] = sqrtf(ss - 8.0f);   // same-wave producer/consumer
  }

  __syncthreads();   // last xt read done (all waves) -> safe to alias as ostg

  // ---- epilogue: bias + rank-1 time term, Lorentz norm (DPP), scatter to LDS ----
  float* ostg = (float*)shmem + wv * 4160;   // this wave's 64px x 65ch row image
#pragma unroll
  for (int mb = 0; mb < 4; ++mb) {
    float4 t4 = *(const float4*)&tres_s[wv * 64 + mb * 16 + q * 4];
#pragma unroll
    for (int r = 0; r < 4; ++r) {
      int pcol = mb * 16 + q * 4 + r;      // C/D row m = quad*4 + reg
      float tr = t4[r];
      float v0 = acc[mb][0][r] + bj[0] + tr * w0j[0];
      float v1 = acc[mb][1][r] + bj[1] + tr * w0j[1];
      float v2 = acc[mb][2][r] + bj[2] + tr * w0j[2];
      float v3 = acc[mb][3][r] + bj[3] + tr * w0j[3];
      float ss = v0 * v0 + v1 * v1 + v2 * v2 + v3 * v3;
      ss = dpp_add<0xB1>(ss);    // + lane^1
      ss = dpp_add<0x4E>(ss);    // + lane^2
      ss = dpp_add<0x141>(ss);   // + mirror-8
      ss = dpp_add<0x140>(ss);   // + mirror-16 (full 16-lane sum)
      float* pb = ostg + pcol * 65;
      if (l15 == 0) pb[0] = sqrtf(ss + 1.0f);
      pb[1 + l15]  = v0;
      pb[17 + l15] = v1;
      pb[33 + l15] = v2;
      pb[49 + l15] = v3;
    }
  }

  // ---- coalesced flush: LDS row image -> global (dense dwordx4) ----
  // Same-wave produce/consume: compiler inserts the lgkmcnt wait; no barrier.
  {
    float* orow = out + (size_t)((bb * 64 + h0 + wv) * 64) * 65;
#pragma unroll
    for (int it = 0; it < 16; ++it) {
      int off = it * 256 + lane * 4;
      *(float4*)(orow + off) = *(const float4*)(ostg + off);
    }
    if (lane < 16) {   // remainder: 4160 - 4096 = 64 floats
      int off = 4096 + lane * 4;
      *(float4*)(orow + off) = *(const float4*)(ostg + off);
    }
  }
}

extern "C" void kernel_launch(void* const* d_in, const int* in_sizes, int n_in,
                              void* d_out, int out_size, void* d_ws, size_t ws_size,
                              hipStream_t stream) {
  const float* x = (const float*)d_in[0];
  const float* w = (const float*)d_in[1];
  const float* b = (const float*)d_in[2];
  float* out = (float*)d_out;
  short* wfragg = (short*)d_ws;   // 73728 B fragment-packed bf16 weight

  prep_weight<<<144, 256, 0, stream>>>(w, wfragg);
  lconv_main<<<32 * 16, 256, 0, stream>>>(x, w, b, wfragg, out);
}